// Round 1
// baseline (2735.661 us; speedup 1.0000x reference)
//
#include <hip/hip_runtime.h>

#define NCHUNK 8

// ---------------------------------------------------------------- reductions
__device__ __forceinline__ void blockReduce2(float& a, float& b, float* r1, float* r2){
  #pragma unroll
  for (int m = 32; m >= 1; m >>= 1){ a += __shfl_xor(a, m); b += __shfl_xor(b, m); }
  int lane = threadIdx.x & 63, w = threadIdx.x >> 6;
  int nw = blockDim.x >> 6;
  if (lane == 0){ r1[w] = a; r2[w] = b; }
  __syncthreads();
  float sa = 0.f, sb = 0.f;
  for (int i = 0; i < nw; ++i){ sa += r1[i]; sb += r2[i]; }
  __syncthreads();
  a = sa; b = sb;
}

// ---------------------------------------------------------------- seg offsets
__global__ void segoff_k(const int* __restrict__ pb, int* __restrict__ seg){
  int t = threadIdx.x;
  if (t > 128) return;
  int lo = 0, hi = 65536;
  while (lo < hi){ int mid = (lo + hi) >> 1; if (pb[mid] < t) lo = mid + 1; else hi = mid; }
  seg[t] = lo;
}

// ---------------------------------------------------------------- LN of x (1024) -> two affines
__global__ __launch_bounds__(256) void ln_x_k(const float* __restrict__ x,
    const float* __restrict__ fpg, const float* __restrict__ fpb,
    const float* __restrict__ gdg, const float* __restrict__ gdb,
    float* __restrict__ xln1, float* __restrict__ xln2)
{
  __shared__ float r1[4], r2[4];
  int b = blockIdx.x, t = threadIdx.x;
  const float* xr = x + (size_t)b * 1024;
  float v[4]; float s = 0.f, ss = 0.f;
  #pragma unroll
  for (int i = 0; i < 4; ++i){ v[i] = xr[t + i*256]; s += v[i]; ss += v[i]*v[i]; }
  blockReduce2(s, ss, r1, r2);
  float mean = s * (1.f/1024.f);
  float var  = ss * (1.f/1024.f) - mean*mean;
  float rstd = rsqrtf(var + 1e-5f);
  #pragma unroll
  for (int i = 0; i < 4; ++i){
    int idx = t + i*256;
    float nrm = (v[i] - mean) * rstd;
    xln1[(size_t)b*1024 + idx] = nrm * fpg[idx] + fpb[idx];
    xln2[(size_t)b*1024 + idx] = nrm * gdg[idx] + gdb[idx];
  }
}

// ---------------------------------------------------------------- LN over rows of 128
__global__ __launch_bounds__(128) void ln_rows_k(const float* __restrict__ in, float* __restrict__ out,
    const float* __restrict__ g, const float* __restrict__ bb)
{
  __shared__ float r1[2], r2[2];
  int r = blockIdx.x, t = threadIdx.x;
  float v = in[(size_t)r*128 + t];
  float s = v, ss = v*v;
  #pragma unroll
  for (int m = 32; m >= 1; m >>= 1){ s += __shfl_xor(s, m); ss += __shfl_xor(ss, m); }
  int lane = t & 63, w = t >> 6;
  if (lane == 0){ r1[w] = s; r2[w] = ss; }
  __syncthreads();
  s = r1[0] + r1[1]; ss = r2[0] + r2[1];
  float mean = s * (1.f/128.f);
  float var  = ss * (1.f/128.f) - mean*mean;
  float rstd = rsqrtf(var + 1e-5f);
  out[(size_t)r*128 + t] = (v - mean) * rstd * g[t] + bb[t];
}

// ---------------------------------------------------------------- generic fp32 GEMM: C = act(A@W + bias)
// A: M x K (lda), W: K x N row-major, C: M x N (ldc). Tile 64 rows x 128 cols, BK=32.
// Requires M%64==0, N%128==0, K%32==0 (true for all call sites).
template<int ACT>  // 0 none, 1 relu, 2 exact gelu
__global__ __launch_bounds__(256) void gemm_k(
    const float* __restrict__ A, const float* __restrict__ W,
    const float* __restrict__ bias, float* __restrict__ C,
    int M, int N, int K, int lda, int ldc)
{
  (void)M;
  __shared__ float a_lds[32][64];    // [k][row] transposed
  __shared__ float b_lds[32][128];   // [k][col]
  int t  = threadIdx.x;
  int m0 = blockIdx.x * 64;
  int n0 = blockIdx.y * 128;
  int tc = t & 15, tr = t >> 4;      // 16x16 thread grid: 4 rows x 8 cols micro-tile
  float acc[4][8];
  #pragma unroll
  for (int i = 0; i < 4; ++i)
    #pragma unroll
    for (int j = 0; j < 8; ++j) acc[i][j] = 0.f;

  int arow = t >> 2;            // 0..63
  int akq  = (t & 3) << 3;      // 0,8,16,24
  int bkk  = t >> 3;            // 0..31
  int bcq  = (t & 7) << 4;      // 0..112

  for (int k0 = 0; k0 < K; k0 += 32){
    const float* ap = A + (size_t)(m0 + arow) * lda + k0 + akq;
    float4 av0 = *(const float4*)ap;
    float4 av1 = *(const float4*)(ap + 4);
    const float* wp = W + (size_t)(k0 + bkk) * N + n0 + bcq;
    float4 bv0 = *(const float4*)wp;
    float4 bv1 = *(const float4*)(wp + 4);
    float4 bv2 = *(const float4*)(wp + 8);
    float4 bv3 = *(const float4*)(wp + 12);
    __syncthreads();
    a_lds[akq+0][arow] = av0.x; a_lds[akq+1][arow] = av0.y;
    a_lds[akq+2][arow] = av0.z; a_lds[akq+3][arow] = av0.w;
    a_lds[akq+4][arow] = av1.x; a_lds[akq+5][arow] = av1.y;
    a_lds[akq+6][arow] = av1.z; a_lds[akq+7][arow] = av1.w;
    *(float4*)&b_lds[bkk][bcq]      = bv0;
    *(float4*)&b_lds[bkk][bcq + 4]  = bv1;
    *(float4*)&b_lds[bkk][bcq + 8]  = bv2;
    *(float4*)&b_lds[bkk][bcq + 12] = bv3;
    __syncthreads();
    #pragma unroll
    for (int kk = 0; kk < 32; ++kk){
      float4 a4  = *(float4*)&a_lds[kk][tr << 2];
      float4 b40 = *(float4*)&b_lds[kk][tc << 3];
      float4 b41 = *(float4*)&b_lds[kk][(tc << 3) + 4];
      float av[4] = {a4.x, a4.y, a4.z, a4.w};
      float bv[8] = {b40.x, b40.y, b40.z, b40.w, b41.x, b41.y, b41.z, b41.w};
      #pragma unroll
      for (int i = 0; i < 4; ++i)
        #pragma unroll
        for (int j = 0; j < 8; ++j) acc[i][j] += av[i] * bv[j];
    }
  }
  #pragma unroll
  for (int i = 0; i < 4; ++i){
    float* cp = C + (size_t)(m0 + (tr << 2) + i) * ldc + n0 + (tc << 3);
    #pragma unroll
    for (int j = 0; j < 8; ++j){
      float v = acc[i][j];
      if (bias) v += bias[n0 + (tc << 3) + j];
      if (ACT == 1) v = fmaxf(v, 0.f);
      if (ACT == 2) v = 0.5f * v * (1.f + erff(v * 0.70710678118654752f));
      cp[j] = v;
    }
  }
}

// ---------------------------------------------------------------- fused k / score / online segment softmax / att_pro partials
// grid = 128 segments x NCHUNK chunks; block 256.
// Per chunk: for each l, k[n,l,:] = relu(prot[n] @ ak_w[l] + ak_b[l]) is computed once
// (held in registers), score = k . am_wk[l] (qscore dropped: softmax shift-invariant),
// online softmax (m,s) with rescaled accumulator. Writes (m[10], s[10], acc[10][128]).
__global__ __launch_bounds__(256) void seg_attn_k(
    const float* __restrict__ prot, const float* __restrict__ ak_w,
    const float* __restrict__ ak_b, const float* __restrict__ am_w,
    const int* __restrict__ seg_off, float* __restrict__ part)
{
  __shared__ float ak_lds[64][128];      // half of ak_w[l] (kk-half)
  __shared__ float prot_lds[2][32][64];  // two 32-row tiles, kk-half
  __shared__ float score_lds[2][32];
  __shared__ float w_lds[2][32];
  __shared__ float m_lds[10], s_lds[10];
  __shared__ float scale_lds[2];
  __shared__ float red[128];

  int t  = threadIdx.x;
  int bc = blockIdx.x;
  int b  = bc >> 3, c = bc & (NCHUNK - 1);
  int lo = seg_off[b], hi = seg_off[b + 1];
  int len  = hi - lo;
  int c_lo = lo + (len * c) / NCHUNK;
  int c_hi = lo + (len * (c + 1)) / NCHUNK;
  int h_grp = t & 31, n_grp = t >> 5;   // h = h_grp*4+j, n = n_grp*4+i (per tile)

  if (t < 10){ m_lds[t] = -1e30f; s_lds[t] = 0.f; }
  float acc[10][4];
  #pragma unroll
  for (int l = 0; l < 10; ++l){ acc[l][0]=0.f; acc[l][1]=0.f; acc[l][2]=0.f; acc[l][3]=0.f; }

  for (int s0 = c_lo; s0 < c_hi; s0 += 64){
    int nvalid = c_hi - s0; if (nvalid > 64) nvalid = 64;
    for (int l = 0; l < 10; ++l){
      float kreg[2][4][4];
      #pragma unroll
      for (int a = 0; a < 2; ++a)
        #pragma unroll
        for (int i = 0; i < 4; ++i)
          #pragma unroll
          for (int j = 0; j < 4; ++j) kreg[a][i][j] = 0.f;

      for (int half = 0; half < 2; ++half){
        __syncthreads();                       // protect LDS from previous phase's readers
        const float* aksrc = ak_w + ((size_t)l * 128 + half * 64) * 128;
        #pragma unroll
        for (int i = 0; i < 8; ++i){           // stage 64x128 ak half (32 KB)
          int f  = t + i * 256;
          int kk = f >> 5;
          int h4 = (f & 31) << 2;
          *(float4*)&ak_lds[kk][h4] = *(const float4*)&aksrc[kk * 128 + h4];
        }
        #pragma unroll
        for (int i = 0; i < 4; ++i){           // stage 2 x 32 x 64 prot half (16 KB)
          int f    = t + i * 256;
          int tile = f >> 9;
          int rem  = f & 511;
          int n    = rem >> 4;
          int k4   = (rem & 15) << 2;
          int ng   = s0 + tile * 32 + n;
          float4 val = make_float4(0.f, 0.f, 0.f, 0.f);
          if (ng < c_hi) val = *(const float4*)&prot[(size_t)ng * 128 + half * 64 + k4];
          *(float4*)&prot_lds[tile][n][k4] = val;
        }
        __syncthreads();
        #pragma unroll
        for (int kq = 0; kq < 16; ++kq){
          float4 w4[4];
          #pragma unroll
          for (int dk = 0; dk < 4; ++dk) w4[dk] = *(float4*)&ak_lds[kq*4 + dk][h_grp << 2];
          #pragma unroll
          for (int tile = 0; tile < 2; ++tile){
            #pragma unroll
            for (int i = 0; i < 4; ++i){
              float4 p = *(float4*)&prot_lds[tile][(n_grp << 2) + i][kq << 2];
              kreg[tile][i][0] += p.x*w4[0].x + p.y*w4[1].x + p.z*w4[2].x + p.w*w4[3].x;
              kreg[tile][i][1] += p.x*w4[0].y + p.y*w4[1].y + p.z*w4[2].y + p.w*w4[3].y;
              kreg[tile][i][2] += p.x*w4[0].z + p.y*w4[1].z + p.z*w4[2].z + p.w*w4[3].z;
              kreg[tile][i][3] += p.x*w4[0].w + p.y*w4[1].w + p.z*w4[2].w + p.w*w4[3].w;
            }
          }
        }
      } // half

      // bias + relu + per-thread score partials, reduce over h groups (32 lanes)
      float4 b4  = *(const float4*)&ak_b[l * 128 + (h_grp << 2)];
      float4 wk4 = *(const float4*)&am_w[l * 256 + (h_grp << 2)];   // am_wk = am_w[:, :128]
      #pragma unroll
      for (int tile = 0; tile < 2; ++tile){
        float ps[4];
        #pragma unroll
        for (int i = 0; i < 4; ++i){
          float k0 = fmaxf(kreg[tile][i][0] + b4.x, 0.f);
          float k1 = fmaxf(kreg[tile][i][1] + b4.y, 0.f);
          float k2 = fmaxf(kreg[tile][i][2] + b4.z, 0.f);
          float k3 = fmaxf(kreg[tile][i][3] + b4.w, 0.f);
          kreg[tile][i][0] = k0; kreg[tile][i][1] = k1;
          kreg[tile][i][2] = k2; kreg[tile][i][3] = k3;
          ps[i] = k0*wk4.x + k1*wk4.y + k2*wk4.z + k3*wk4.w;
        }
        #pragma unroll
        for (int m = 16; m >= 1; m >>= 1){
          #pragma unroll
          for (int i = 0; i < 4; ++i) ps[i] += __shfl_xor(ps[i], m);
        }
        if (h_grp == 0){
          #pragma unroll
          for (int i = 0; i < 4; ++i) score_lds[tile][(n_grp << 2) + i] = ps[i];
        }
      }
      __syncthreads();

      // online softmax bookkeeping (tiles sequential: tile1 sees tile0-updated m)
      for (int tile = 0; tile < 2; ++tile){
        int nt = nvalid - tile * 32; nt = nt < 0 ? 0 : (nt > 32 ? 32 : nt);
        if (nt > 0 && t < 32){
          float sc = (t < nt) ? score_lds[tile][t] : -3e38f;
          float mx = sc;
          #pragma unroll
          for (int m = 16; m >= 1; m >>= 1) mx = fmaxf(mx, __shfl_xor(mx, m));
          float oldm = m_lds[l];
          float newm = fmaxf(oldm, mx);
          float w = (t < nt) ? __expf(sc - newm) : 0.f;
          w_lds[tile][t] = w;
          float wsum = w;
          #pragma unroll
          for (int m = 16; m >= 1; m >>= 1) wsum += __shfl_xor(wsum, m);
          if (t == 0){
            float scale = __expf(oldm - newm);
            s_lds[l] = s_lds[l] * scale + wsum;
            m_lds[l] = newm;
            scale_lds[tile] = scale;
          }
        }
        __syncthreads();
      }

      // accumulator update (static acc indexing via predicated unroll)
      for (int tile = 0; tile < 2; ++tile){
        int nt = nvalid - tile * 32;
        if (nt > 0){
          float scl = scale_lds[tile];
          float wv0 = w_lds[tile][(n_grp << 2) + 0];
          float wv1 = w_lds[tile][(n_grp << 2) + 1];
          float wv2 = w_lds[tile][(n_grp << 2) + 2];
          float wv3 = w_lds[tile][(n_grp << 2) + 3];
          #pragma unroll
          for (int ll = 0; ll < 10; ++ll) if (ll == l){
            #pragma unroll
            for (int j = 0; j < 4; ++j){
              acc[ll][j] = acc[ll][j] * scl
                + wv0 * kreg[tile][0][j] + wv1 * kreg[tile][1][j]
                + wv2 * kreg[tile][2][j] + wv3 * kreg[tile][3][j];
            }
          }
        }
      }
    } // l
  } // s0

  // epilogue: reduce acc across n groups, write partial
  __syncthreads();
  size_t base = (size_t)bc * 1300;   // [m 10][s 10][acc 10*128]
  for (int l = 0; l < 10; ++l){
    if (t < 128) red[t] = 0.f;
    __syncthreads();
    float a0=0.f, a1=0.f, a2=0.f, a3=0.f;
    #pragma unroll
    for (int ll = 0; ll < 10; ++ll) if (ll == l){ a0=acc[ll][0]; a1=acc[ll][1]; a2=acc[ll][2]; a3=acc[ll][3]; }
    atomicAdd(&red[(h_grp << 2) + 0], a0);
    atomicAdd(&red[(h_grp << 2) + 1], a1);
    atomicAdd(&red[(h_grp << 2) + 2], a2);
    atomicAdd(&red[(h_grp << 2) + 3], a3);
    __syncthreads();
    if (t < 128) part[base + 20 + l * 128 + t] = red[t];
    __syncthreads();
  }
  if (t < 10){ part[base + t] = m_lds[t]; part[base + 10 + t] = s_lds[t]; }
}

// ---------------------------------------------------------------- merge chunk partials -> att_pro, att_mean
__global__ __launch_bounds__(128) void merge_k(const float* __restrict__ part,
    float* __restrict__ att_pro, float* __restrict__ att_mean)
{
  __shared__ float ms[NCHUNK][10], ssb[NCHUNK][10];
  int b = blockIdx.x, t = threadIdx.x;  // t = h
  if (t < NCHUNK * 10){
    int c = t / 10, l = t % 10;
    size_t base = ((size_t)(b * NCHUNK + c)) * 1300;
    ms[c][l]  = part[base + l];
    ssb[c][l] = part[base + 10 + l];
  }
  __syncthreads();
  float amean = 0.f;
  for (int l = 0; l < 10; ++l){
    float M = -3e38f;
    for (int c = 0; c < NCHUNK; ++c) M = fmaxf(M, ms[c][l]);
    float att = 0.f, S = 0.f;
    for (int c = 0; c < NCHUNK; ++c){
      float e = __expf(ms[c][l] - M);
      S   += e * ssb[c][l];
      att += e * part[((size_t)(b * NCHUNK + c)) * 1300 + 20 + l * 128 + t];
    }
    float o = att / (S + 1e-16f);
    att_pro[((size_t)b * 10 + l) * 128 + t] = o;
    amean += o;
  }
  att_mean[(size_t)b * 128 + t] = amean * 0.1f;
}

// ---------------------------------------------------------------- per-b tail: pools + output MLP
__global__ __launch_bounds__(256) void final_k(
    const float* __restrict__ qall, const float* __restrict__ Kp,
    const float* __restrict__ P, const float* __restrict__ Kd,
    const float* __restrict__ dtok,
    const float* __restrict__ o1w, const float* __restrict__ o1b, const float* __restrict__ pr1,
    const float* __restrict__ o2w, const float* __restrict__ o2b, const float* __restrict__ pr2,
    const float* __restrict__ o3w, const float* __restrict__ o3b,
    float* __restrict__ out)
{
  __shared__ float qa[128];
  __shared__ float sp[10], sd[16], wp[10], wdd[16];
  __shared__ float vcat[256];
  __shared__ float h1[512];
  __shared__ float h2[128];
  __shared__ float redw[4];
  int b = blockIdx.x, t = threadIdx.x;
  if (t < 128) qa[t] = qall[(size_t)b * 128 + t];
  __syncthreads();
  if (t < 10){
    const float* kp = Kp + ((size_t)b * 10 + t) * 128;
    float s = 0.f;
    for (int h = 0; h < 128; ++h) s += qa[h] * kp[h];
    sp[t] = s * 0.088388347648318447f;  // 1/sqrt(128)
  } else if (t >= 64 && t < 80){
    int j = t - 64;
    const float* kd = Kd + ((size_t)b * 16 + j) * 128;
    float s = 0.f;
    for (int h = 0; h < 128; ++h) s += qa[h] * kd[h];
    sd[j] = s * 0.088388347648318447f;
  }
  __syncthreads();
  if (t == 0){
    float mx = -3e38f;
    for (int j = 0; j < 10; ++j) mx = fmaxf(mx, sp[j]);
    float sum = 0.f;
    for (int j = 0; j < 10; ++j) sum += __expf(sp[j] - mx);
    float inv = 1.f / sum;
    for (int j = 0; j < 10; ++j) wp[j] = __expf(sp[j] - mx) * inv;
  } else if (t == 64){
    float mx = -3e38f;
    for (int j = 0; j < 16; ++j) mx = fmaxf(mx, sd[j]);
    float sum = 0.f;
    for (int j = 0; j < 16; ++j) sum += __expf(sd[j] - mx);
    float inv = 1.f / sum;
    for (int j = 0; j < 16; ++j) wdd[j] = __expf(sd[j] - mx) * inv;
  }
  __syncthreads();
  if (t < 128){
    float vd = 0.f, vp = 0.f;
    for (int j = 0; j < 16; ++j) vd += wdd[j] * dtok[((size_t)b * 16 + j) * 128 + t];
    for (int j = 0; j < 10; ++j) vp += wp[j]  * P[((size_t)b * 10 + j) * 128 + t];
    vcat[t] = vd; vcat[128 + t] = vp;
  }
  __syncthreads();
  {
    float p1 = pr1[0];
    float a1 = o1b[t], a2 = o1b[t + 256];
    for (int k = 0; k < 256; ++k){
      float v = vcat[k];
      a1 += v * o1w[(size_t)k * 512 + t];
      a2 += v * o1w[(size_t)k * 512 + t + 256];
    }
    h1[t]       = a1 > 0.f ? a1 : p1 * a1;
    h1[t + 256] = a2 > 0.f ? a2 : p1 * a2;
  }
  __syncthreads();
  if (t < 128){
    float p2 = pr2[0];
    float a = o2b[t];
    for (int k = 0; k < 512; ++k) a += h1[k] * o2w[(size_t)k * 128 + t];
    h2[t] = a > 0.f ? a : p2 * a;
  }
  __syncthreads();
  float v = (t < 128) ? h2[t] * o3w[t] : 0.f;
  #pragma unroll
  for (int m = 32; m >= 1; m >>= 1) v += __shfl_xor(v, m);
  if ((t & 63) == 0) redw[t >> 6] = v;
  __syncthreads();
  if (t == 0) out[b] = redw[0] + redw[1] + redw[2] + redw[3] + o3b[0];
}

// ---------------------------------------------------------------- launch
extern "C" void kernel_launch(void* const* d_in, const int* in_sizes, int n_in,
                              void* d_out, int out_size, void* d_ws, size_t ws_size,
                              hipStream_t stream)
{
  (void)in_sizes; (void)n_in; (void)out_size;
  const float* x        = (const float*)d_in[0];
  const float* pro_emb  = (const float*)d_in[1];
  const int*   pro_batch= (const int*)d_in[2];
  // r_w1..r_b4 (3..10), aq_w (12), aq_b (13): dead — softmax is shift-invariant per segment.
  const float* prej2_w  = (const float*)d_in[11];
  const float* ak_w     = (const float*)d_in[14];
  const float* ak_b     = (const float*)d_in[15];
  const float* am_w     = (const float*)d_in[16];
  const float* fpln_g   = (const float*)d_in[17];
  const float* fpln_b   = (const float*)d_in[18];
  const float* fpproj_w = (const float*)d_in[19];
  const float* fpproj_b = (const float*)d_in[20];
  const float* gdln_g   = (const float*)d_in[21];
  const float* gdln_b   = (const float*)d_in[22];
  const float* gd1_w    = (const float*)d_in[23];
  const float* gd1_b    = (const float*)d_in[24];
  const float* gd2_w    = (const float*)d_in[25];
  const float* gd2_b    = (const float*)d_in[26];
  const float* gp_w     = (const float*)d_in[27];
  const float* gp_b     = (const float*)d_in[28];
  const float* q_w      = (const float*)d_in[29];
  const float* q_b      = (const float*)d_in[30];
  const float* lnd_g    = (const float*)d_in[31];
  const float* lnd_b    = (const float*)d_in[32];
  const float* kd_w     = (const float*)d_in[33];
  const float* kd_b     = (const float*)d_in[34];
  const float* lnp_g    = (const float*)d_in[35];
  const float* lnp_b    = (const float*)d_in[36];
  const float* kp_w     = (const float*)d_in[37];
  const float* kp_b     = (const float*)d_in[38];
  const float* o1_w     = (const float*)d_in[39];
  const float* o1_b     = (const float*)d_in[40];
  const float* pr1      = (const float*)d_in[41];
  const float* o2_w     = (const float*)d_in[42];
  const float* o2_b     = (const float*)d_in[43];
  const float* pr2      = (const float*)d_in[44];
  const float* o3_w     = (const float*)d_in[45];
  const float* o3_b     = (const float*)d_in[46];
  float* out = (float*)d_out;

  float* W = (float*)d_ws;
  size_t off = 0;
  int*   seg  = (int*)W;        off += 256;
  float* prot = W + off;        off += (size_t)65536 * 128;
  float* xln1 = W + off;        off += 128 * 1024;
  float* xln2 = W + off;        off += 128 * 1024;
  float* dtp  = W + off;        off += 128 * 2048;
  float* dtok = W + off;        off += 128 * 2048;
  float* Kd   = W + off;        off += 128 * 2048;
  float* gd1t = W + off;        off += 128 * 128;
  float* gbuf = W + off;        off += 128 * 256;   // [g_d | g_p]
  float* qall = W + off;        off += 128 * 128;
  float* attp = W + off;        off += 128 * 10 * 128;
  float* attm = W + off;        off += 128 * 128;
  float* Pm   = W + off;        off += 128 * 10 * 128;
  float* Kp   = W + off;        off += 128 * 10 * 128;
  float* part = W + off;        off += (size_t)128 * NCHUNK * 1300;
  if (ws_size < off * sizeof(float)) return;  // loud failure (output stays poisoned)

  segoff_k<<<1, 256, 0, stream>>>(pro_batch, seg);
  ln_x_k<<<128, 256, 0, stream>>>(x, fpln_g, fpln_b, gdln_g, gdln_b, xln1, xln2);
  // prot = relu(pro_emb @ prej2_w)   [65536 x 1280 x 128]
  gemm_k<1><<<dim3(1024, 1), 256, 0, stream>>>(pro_emb, prej2_w, nullptr, prot, 65536, 128, 1280, 1280, 128);
  // d_tok_pre = LN(x)@fpproj + b     [128 x 1024 x 2048]
  gemm_k<0><<<dim3(2, 16), 256, 0, stream>>>(xln1, fpproj_w, fpproj_b, dtp, 128, 2048, 1024, 1024, 2048);
  ln_rows_k<<<2048, 128, 0, stream>>>(dtp, dtok, lnd_g, lnd_b);
  gemm_k<0><<<dim3(32, 1), 256, 0, stream>>>(dtok, kd_w, kd_b, Kd, 2048, 128, 128, 128, 128);
  // g_d = gelu(LN(x)@gd1 + b)@gd2 + b
  gemm_k<2><<<dim3(2, 1), 256, 0, stream>>>(xln2, gd1_w, gd1_b, gd1t, 128, 128, 1024, 1024, 128);
  gemm_k<0><<<dim3(2, 1), 256, 0, stream>>>(gd1t, gd2_w, gd2_b, gbuf, 128, 128, 128, 128, 256);
  // fused k/score/segment-softmax partials
  seg_attn_k<<<128 * NCHUNK, 256, 0, stream>>>(prot, ak_w, ak_b, am_w, seg, part);
  merge_k<<<128, 128, 0, stream>>>(part, attp, attm);
  // g_p = gelu(att_mean@gp + b) into gbuf cols 128..255
  gemm_k<2><<<dim3(2, 1), 256, 0, stream>>>(attm, gp_w, gp_b, gbuf + 128, 128, 128, 128, 128, 256);
  // q_all = [g_d, g_p] @ q_w + q_b
  gemm_k<0><<<dim3(2, 1), 256, 0, stream>>>(gbuf, q_w, q_b, qall, 128, 128, 256, 256, 128);
  ln_rows_k<<<1280, 128, 0, stream>>>(attp, Pm, lnp_g, lnp_b);
  gemm_k<0><<<dim3(20, 1), 256, 0, stream>>>(Pm, kp_w, kp_b, Kp, 1280, 128, 128, 128, 128);
  final_k<<<128, 256, 0, stream>>>(qall, Kp, Pm, Kd, dtok,
      o1_w, o1_b, pr1, o2_w, o2_b, pr2, o3_w, o3_b, out);
}

// Round 3
// 1061.081 us; speedup vs baseline: 2.5782x; 2.5782x over previous
//
#include <hip/hip_runtime.h>

#define NCHUNK 8

typedef __attribute__((ext_vector_type(8))) short bf16x8;
typedef __attribute__((ext_vector_type(4))) float f32x4;

__device__ __forceinline__ unsigned short f2b(float f){
  unsigned int u = __float_as_uint(f);
  unsigned int r = (u + 0x7FFFu + ((u >> 16) & 1u)) >> 16;
  return (unsigned short)r;
}

// ---------------------------------------------------------------- reductions
__device__ __forceinline__ void blockReduce2(float& a, float& b, float* r1, float* r2){
  #pragma unroll
  for (int m = 32; m >= 1; m >>= 1){ a += __shfl_xor(a, m); b += __shfl_xor(b, m); }
  int lane = threadIdx.x & 63, w = threadIdx.x >> 6;
  int nw = blockDim.x >> 6;
  if (lane == 0){ r1[w] = a; r2[w] = b; }
  __syncthreads();
  float sa = 0.f, sb = 0.f;
  for (int i = 0; i < nw; ++i){ sa += r1[i]; sb += r2[i]; }
  __syncthreads();
  a = sa; b = sb;
}

// ---------------------------------------------------------------- seg offsets
__global__ void segoff_k(const int* __restrict__ pb, int* __restrict__ seg){
  int t = threadIdx.x;
  if (t > 128) return;
  int lo = 0, hi = 65536;
  while (lo < hi){ int mid = (lo + hi) >> 1; if (pb[mid] < t) lo = mid + 1; else hi = mid; }
  seg[t] = lo;
}

// ---------------------------------------------------------------- weight converts
// prejT[n][k] = bf16(prej2_w[k][n]) : [128][1280]
__global__ __launch_bounds__(256) void cvt_prejT_k(const float* __restrict__ w, unsigned short* __restrict__ o){
  int i = blockIdx.x * 256 + threadIdx.x;
  if (i >= 163840) return;
  int n = i & 127, k = i >> 7;
  o[n * 1280 + k] = f2b(w[k * 128 + n]);
}
// akwT[l][ho][hi] = bf16(ak_w[l][hi][ho]) : [10][128][128]
__global__ __launch_bounds__(256) void cvt_akwT_k(const float* __restrict__ w, unsigned short* __restrict__ o){
  int i = blockIdx.x * 256 + threadIdx.x;
  if (i >= 163840) return;
  int l = i >> 14, r = i & 16383;
  int ho = r >> 7, hi = r & 127;
  o[i] = f2b(w[(l * 128 + hi) * 128 + ho]);
}

// ---------------------------------------------------------------- LN of x (1024) -> two affines
__global__ __launch_bounds__(256) void ln_x_k(const float* __restrict__ x,
    const float* __restrict__ fpg, const float* __restrict__ fpb,
    const float* __restrict__ gdg, const float* __restrict__ gdb,
    float* __restrict__ xln1, float* __restrict__ xln2)
{
  __shared__ float r1[4], r2[4];
  int b = blockIdx.x, t = threadIdx.x;
  const float* xr = x + (size_t)b * 1024;
  float v[4]; float s = 0.f, ss = 0.f;
  #pragma unroll
  for (int i = 0; i < 4; ++i){ v[i] = xr[t + i*256]; s += v[i]; ss += v[i]*v[i]; }
  blockReduce2(s, ss, r1, r2);
  float mean = s * (1.f/1024.f);
  float var  = ss * (1.f/1024.f) - mean*mean;
  float rstd = rsqrtf(var + 1e-5f);
  #pragma unroll
  for (int i = 0; i < 4; ++i){
    int idx = t + i*256;
    float nrm = (v[i] - mean) * rstd;
    xln1[(size_t)b*1024 + idx] = nrm * fpg[idx] + fpb[idx];
    xln2[(size_t)b*1024 + idx] = nrm * gdg[idx] + gdb[idx];
  }
}

// ---------------------------------------------------------------- LN over rows of 128
__global__ __launch_bounds__(128) void ln_rows_k(const float* __restrict__ in, float* __restrict__ out,
    const float* __restrict__ g, const float* __restrict__ bb)
{
  __shared__ float r1[2], r2[2];
  int r = blockIdx.x, t = threadIdx.x;
  float v = in[(size_t)r*128 + t];
  float s = v, ss = v*v;
  #pragma unroll
  for (int m = 32; m >= 1; m >>= 1){ s += __shfl_xor(s, m); ss += __shfl_xor(ss, m); }
  int lane = t & 63, w = t >> 6;
  if (lane == 0){ r1[w] = s; r2[w] = ss; }
  __syncthreads();
  s = r1[0] + r1[1]; ss = r2[0] + r2[1];
  float mean = s * (1.f/128.f);
  float var  = ss * (1.f/128.f) - mean*mean;
  float rstd = rsqrtf(var + 1e-5f);
  out[(size_t)r*128 + t] = (v - mean) * rstd * g[t] + bb[t];
}

// ---------------------------------------------------------------- generic fp32 GEMM (small ops only)
template<int ACT>  // 0 none, 1 relu, 2 exact gelu
__global__ __launch_bounds__(256) void gemm_k(
    const float* __restrict__ A, const float* __restrict__ W,
    const float* __restrict__ bias, float* __restrict__ C,
    int M, int N, int K, int lda, int ldc)
{
  (void)M;
  __shared__ float a_lds[32][64];
  __shared__ float b_lds[32][128];
  int t  = threadIdx.x;
  int m0 = blockIdx.x * 64;
  int n0 = blockIdx.y * 128;
  int tc = t & 15, tr = t >> 4;
  float acc[4][8];
  #pragma unroll
  for (int i = 0; i < 4; ++i)
    #pragma unroll
    for (int j = 0; j < 8; ++j) acc[i][j] = 0.f;

  int arow = t >> 2;
  int akq  = (t & 3) << 3;
  int bkk  = t >> 3;
  int bcq  = (t & 7) << 4;

  for (int k0 = 0; k0 < K; k0 += 32){
    const float* ap = A + (size_t)(m0 + arow) * lda + k0 + akq;
    float4 av0 = *(const float4*)ap;
    float4 av1 = *(const float4*)(ap + 4);
    const float* wp = W + (size_t)(k0 + bkk) * N + n0 + bcq;
    float4 bv0 = *(const float4*)wp;
    float4 bv1 = *(const float4*)(wp + 4);
    float4 bv2 = *(const float4*)(wp + 8);
    float4 bv3 = *(const float4*)(wp + 12);
    __syncthreads();
    a_lds[akq+0][arow] = av0.x; a_lds[akq+1][arow] = av0.y;
    a_lds[akq+2][arow] = av0.z; a_lds[akq+3][arow] = av0.w;
    a_lds[akq+4][arow] = av1.x; a_lds[akq+5][arow] = av1.y;
    a_lds[akq+6][arow] = av1.z; a_lds[akq+7][arow] = av1.w;
    *(float4*)&b_lds[bkk][bcq]      = bv0;
    *(float4*)&b_lds[bkk][bcq + 4]  = bv1;
    *(float4*)&b_lds[bkk][bcq + 8]  = bv2;
    *(float4*)&b_lds[bkk][bcq + 12] = bv3;
    __syncthreads();
    #pragma unroll
    for (int kk = 0; kk < 32; ++kk){
      float4 a4  = *(float4*)&a_lds[kk][tr << 2];
      float4 b40 = *(float4*)&b_lds[kk][tc << 3];
      float4 b41 = *(float4*)&b_lds[kk][(tc << 3) + 4];
      float av[4] = {a4.x, a4.y, a4.z, a4.w};
      float bv[8] = {b40.x, b40.y, b40.z, b40.w, b41.x, b41.y, b41.z, b41.w};
      #pragma unroll
      for (int i = 0; i < 4; ++i)
        #pragma unroll
        for (int j = 0; j < 8; ++j) acc[i][j] += av[i] * bv[j];
    }
  }
  #pragma unroll
  for (int i = 0; i < 4; ++i){
    float* cp = C + (size_t)(m0 + (tr << 2) + i) * ldc + n0 + (tc << 3);
    #pragma unroll
    for (int j = 0; j < 8; ++j){
      float v = acc[i][j];
      if (bias) v += bias[n0 + (tc << 3) + j];
      if (ACT == 1) v = fmaxf(v, 0.f);
      if (ACT == 2) v = 0.5f * v * (1.f + erff(v * 0.70710678118654752f));
      cp[j] = v;
    }
  }
}

// ---------------------------------------------------------------- MFMA GEMM1: prot = relu(pro_emb @ prej2_w) -> bf16
// A fp32 [65536][1280] reg-staged with in-flight cvt; BT bf16 [128][1280]; C bf16 [65536][128].
// Tile 128x128, BK=32, 4 waves (2x2), each 64x64 = 4x4 frags of 16x16x32.
// LDS k-major: [kslot(8 bf16)][row] x 16B -> fragment ds_read_b128 fully contiguous per 16-lane group.
__global__ __launch_bounds__(256) void gemm1_mfma(
    const float* __restrict__ A, const unsigned short* __restrict__ BT,
    unsigned short* __restrict__ Cout)
{
  __shared__ char Ab[4 * 128 * 16];   // 8 KB
  __shared__ char Bb[4 * 128 * 16];   // 8 KB
  int t = threadIdx.x, lane = t & 63, wid = t >> 6;
  int m0 = blockIdx.x * 128;
  int wr = wid >> 1, wc = wid & 1;
  f32x4 acc[4][4];
  #pragma unroll
  for (int mf = 0; mf < 4; ++mf)
    #pragma unroll
    for (int nf = 0; nf < 4; ++nf) acc[mf][nf] = (f32x4){0.f, 0.f, 0.f, 0.f};

  int srow = t >> 1, shalf = t & 1;
  const float* aptr = A + (size_t)(m0 + srow) * 1280 + shalf * 16;
  const unsigned short* bptr = BT + (size_t)srow * 1280 + shalf * 16;

  for (int kb = 0; kb < 40; ++kb){
    float4 a0 = *(const float4*)(aptr + 0);
    float4 a1 = *(const float4*)(aptr + 4);
    float4 a2 = *(const float4*)(aptr + 8);
    float4 a3 = *(const float4*)(aptr + 12);
    uint4 bv0 = *(const uint4*)(bptr);
    uint4 bv1 = *(const uint4*)(bptr + 8);
    aptr += 32; bptr += 32;
    __syncthreads();   // previous iter's fragment reads complete
    uint4 pa0, pa1;
    pa0.x = (unsigned)f2b(a0.x) | ((unsigned)f2b(a0.y) << 16);
    pa0.y = (unsigned)f2b(a0.z) | ((unsigned)f2b(a0.w) << 16);
    pa0.z = (unsigned)f2b(a1.x) | ((unsigned)f2b(a1.y) << 16);
    pa0.w = (unsigned)f2b(a1.z) | ((unsigned)f2b(a1.w) << 16);
    pa1.x = (unsigned)f2b(a2.x) | ((unsigned)f2b(a2.y) << 16);
    pa1.y = (unsigned)f2b(a2.z) | ((unsigned)f2b(a2.w) << 16);
    pa1.z = (unsigned)f2b(a3.x) | ((unsigned)f2b(a3.y) << 16);
    pa1.w = (unsigned)f2b(a3.z) | ((unsigned)f2b(a3.w) << 16);
    *(uint4*)(Ab + (shalf*2 + 0) * 2048 + srow * 16) = pa0;
    *(uint4*)(Ab + (shalf*2 + 1) * 2048 + srow * 16) = pa1;
    *(uint4*)(Bb + (shalf*2 + 0) * 2048 + srow * 16) = bv0;
    *(uint4*)(Bb + (shalf*2 + 1) * 2048 + srow * 16) = bv1;
    __syncthreads();   // staging complete
    bf16x8 af[4], bf[4];
    #pragma unroll
    for (int mf = 0; mf < 4; ++mf)
      af[mf] = *(bf16x8*)(Ab + (lane >> 4) * 2048 + (wr*64 + mf*16 + (lane & 15)) * 16);
    #pragma unroll
    for (int nf = 0; nf < 4; ++nf)
      bf[nf] = *(bf16x8*)(Bb + (lane >> 4) * 2048 + (wc*64 + nf*16 + (lane & 15)) * 16);
    #pragma unroll
    for (int mf = 0; mf < 4; ++mf)
      #pragma unroll
      for (int nf = 0; nf < 4; ++nf)
        acc[mf][nf] = __builtin_amdgcn_mfma_f32_16x16x32_bf16(af[mf], bf[nf], acc[mf][nf], 0, 0, 0);
  }
  // epilogue: relu -> bf16.  C/D: col=lane&15, row=(lane>>4)*4+reg  [m89]
  #pragma unroll
  for (int mf = 0; mf < 4; ++mf)
    #pragma unroll
    for (int nf = 0; nf < 4; ++nf){
      int col = wc*64 + nf*16 + (lane & 15);
      #pragma unroll
      for (int r = 0; r < 4; ++r){
        int row = m0 + wr*64 + mf*16 + (lane >> 4)*4 + r;
        Cout[(size_t)row * 128 + col] = f2b(fmaxf(acc[mf][nf][r], 0.f));
      }
    }
}

// ---------------------------------------------------------------- MFMA fused k/score/online segment softmax
// grid = 128 segs x NCHUNK; 256 thr (4 waves). Per 64-row tile of prot (bf16), per l:
// stage akwT[l] (32 KB), MFMA k=relu(prot@ak^T+b), score=k.am_wk, online softmax, acc += w*k.
// qscore dropped: softmax shift-invariant per (segment,l). Partial out: [m10][s10][acc 10x128].
__global__ __launch_bounds__(256) void seg_attn_mfma(
    const unsigned short* __restrict__ prot, const unsigned short* __restrict__ akwT,
    const float* __restrict__ ak_b, const float* __restrict__ am_w,
    const int* __restrict__ seg_off, float* __restrict__ part)
{
  __shared__ char Ab[16 * 64 * 16];    // 16 KB  [kslot][row]x16B
  __shared__ char Bb[16 * 128 * 16];   // 32 KB  [kslot][ho]x16B
  __shared__ float accL[10][128];      // 5 KB
  __shared__ float scoreL[4][64];
  __shared__ float wL[64];
  __shared__ float mL[10], sL[10], scaleL;

  int t = threadIdx.x, lane = t & 63, wid = t >> 6;
  int bc = blockIdx.x, b = bc >> 3, c = bc & (NCHUNK - 1);
  int lo = seg_off[b], hi = seg_off[b + 1], len = hi - lo;
  int c_lo = lo + (len * c) / NCHUNK;
  int c_hi = lo + (len * (c + 1)) / NCHUNK;

  for (int i = t; i < 1280; i += 256) ((float*)accL)[i] = 0.f;
  if (t < 10){ mL[t] = -1e30f; sL[t] = 0.f; }
  __syncthreads();

  for (int s0 = c_lo; s0 < c_hi; s0 += 64){
    int nv = c_hi - s0; if (nv > 64) nv = 64;
    __syncthreads();    // previous tile's A readers done
    {   // stage A tile (64 rows, zero-padded)
      int row = t >> 2, q = t & 3;
      const uint4* src = (const uint4*)(prot + (size_t)(s0 + row) * 128) + q * 4;
      uint4 z; z.x = 0; z.y = 0; z.z = 0; z.w = 0;
      #pragma unroll
      for (int i = 0; i < 4; ++i){
        uint4 v = (row < nv) ? src[i] : z;
        *(uint4*)(Ab + (q*4 + i) * 1024 + row * 16) = v;
      }
    }
    for (int l = 0; l < 10; ++l){
      __syncthreads();  // previous l's B readers done (also publishes A on first l)
      {  // stage B = akwT[l] : [128 ho][128 k]
        int row = t >> 1, h = t & 1;
        const uint4* src = (const uint4*)(akwT + ((size_t)l * 128 + row) * 128 + h * 64);
        #pragma unroll
        for (int i = 0; i < 8; ++i)
          *(uint4*)(Bb + (h*8 + i) * 2048 + row * 16) = src[i];
      }
      __syncthreads();

      f32x4 acc[4][2];
      #pragma unroll
      for (int mf = 0; mf < 4; ++mf){ acc[mf][0] = (f32x4){0.f,0.f,0.f,0.f}; acc[mf][1] = (f32x4){0.f,0.f,0.f,0.f}; }
      #pragma unroll
      for (int ks = 0; ks < 4; ++ks){
        bf16x8 af[4], bfr[2];
        #pragma unroll
        for (int mf = 0; mf < 4; ++mf)
          af[mf] = *(bf16x8*)(Ab + (ks*4 + (lane >> 4)) * 1024 + (mf*16 + (lane & 15)) * 16);
        #pragma unroll
        for (int nf = 0; nf < 2; ++nf)
          bfr[nf] = *(bf16x8*)(Bb + (ks*4 + (lane >> 4)) * 2048 + (wid*32 + nf*16 + (lane & 15)) * 16);
        #pragma unroll
        for (int mf = 0; mf < 4; ++mf){
          acc[mf][0] = __builtin_amdgcn_mfma_f32_16x16x32_bf16(af[mf], bfr[0], acc[mf][0], 0, 0, 0);
          acc[mf][1] = __builtin_amdgcn_mfma_f32_16x16x32_bf16(af[mf], bfr[1], acc[mf][1], 0, 0, 0);
        }
      }
      // epilogue: bias+relu, score partials
      int col0 = wid*32 + (lane & 15), col1 = col0 + 16;
      float bias0 = ak_b[l*128 + col0], bias1 = ak_b[l*128 + col1];
      float aw0 = am_w[l*256 + col0],  aw1 = am_w[l*256 + col1];
      float ps[4][4];
      #pragma unroll
      for (int mf = 0; mf < 4; ++mf)
        #pragma unroll
        for (int r = 0; r < 4; ++r){
          float k0 = fmaxf(acc[mf][0][r] + bias0, 0.f);
          float k1 = fmaxf(acc[mf][1][r] + bias1, 0.f);
          acc[mf][0][r] = k0; acc[mf][1][r] = k1;
          ps[mf][r] = k0*aw0 + k1*aw1;
        }
      #pragma unroll
      for (int m = 1; m <= 8; m <<= 1)
        #pragma unroll
        for (int mf = 0; mf < 4; ++mf)
          #pragma unroll
          for (int r = 0; r < 4; ++r) ps[mf][r] += __shfl_xor(ps[mf][r], m);
      if ((lane & 15) == 0){
        int g = lane >> 4;
        #pragma unroll
        for (int mf = 0; mf < 4; ++mf)
          #pragma unroll
          for (int r = 0; r < 4; ++r) scoreL[wid][mf*16 + g*4 + r] = ps[mf][r];
      }
      __syncthreads();
      if (t < 64){   // online softmax over this tile (wave 0)
        float sc = (t < nv) ? (scoreL[0][t] + scoreL[1][t] + scoreL[2][t] + scoreL[3][t]) : -3e38f;
        float mx = sc;
        #pragma unroll
        for (int m = 1; m <= 32; m <<= 1) mx = fmaxf(mx, __shfl_xor(mx, m));
        float oldm = mL[l], newm = fmaxf(oldm, mx);
        float w = (t < nv) ? __expf(sc - newm) : 0.f;
        wL[t] = w;
        float ws = w;
        #pragma unroll
        for (int m = 1; m <= 32; m <<= 1) ws += __shfl_xor(ws, m);
        if (t == 0){
          float scale = __expf(oldm - newm);
          sL[l] = sL[l] * scale + ws;
          mL[l] = newm;
          scaleL = scale;
        }
      }
      __syncthreads();
      if (t < 128) accL[l][t] *= scaleL;
      __syncthreads();
      {  // acc += w * k   (col-sums via shfl over row groups)
        int g = lane >> 4;
        float cs0 = 0.f, cs1 = 0.f;
        #pragma unroll
        for (int mf = 0; mf < 4; ++mf)
          #pragma unroll
          for (int r = 0; r < 4; ++r){
            float wv = wL[mf*16 + g*4 + r];
            cs0 += wv * acc[mf][0][r];
            cs1 += wv * acc[mf][1][r];
          }
        cs0 += __shfl_xor(cs0, 16); cs0 += __shfl_xor(cs0, 32);
        cs1 += __shfl_xor(cs1, 16); cs1 += __shfl_xor(cs1, 32);
        if (lane < 16){
          accL[l][col0] += cs0;
          accL[l][col1] += cs1;
        }
      }
    } // l
  } // s0

  __syncthreads();
  size_t base = (size_t)bc * 1300;
  if (t < 10){ part[base + t] = mL[t]; part[base + 10 + t] = sL[t]; }
  if (t < 128)
    for (int l = 0; l < 10; ++l) part[base + 20 + l*128 + t] = accL[l][t];
}

// ---------------------------------------------------------------- merge chunk partials -> att_pro, att_mean
__global__ __launch_bounds__(128) void merge_k(const float* __restrict__ part,
    float* __restrict__ att_pro, float* __restrict__ att_mean)
{
  __shared__ float ms[NCHUNK][10], ssb[NCHUNK][10];
  int b = blockIdx.x, t = threadIdx.x;
  if (t < NCHUNK * 10){
    int c = t / 10, l = t % 10;
    size_t base = ((size_t)(b * NCHUNK + c)) * 1300;
    ms[c][l]  = part[base + l];
    ssb[c][l] = part[base + 10 + l];
  }
  __syncthreads();
  float amean = 0.f;
  for (int l = 0; l < 10; ++l){
    float M = -3e38f;
    for (int c = 0; c < NCHUNK; ++c) M = fmaxf(M, ms[c][l]);
    float att = 0.f, S = 0.f;
    for (int c = 0; c < NCHUNK; ++c){
      float e = __expf(ms[c][l] - M);
      S   += e * ssb[c][l];
      att += e * part[((size_t)(b * NCHUNK + c)) * 1300 + 20 + l * 128 + t];
    }
    float o = att / (S + 1e-16f);
    att_pro[((size_t)b * 10 + l) * 128 + t] = o;
    amean += o;
  }
  att_mean[(size_t)b * 128 + t] = amean * 0.1f;
}

// ---------------------------------------------------------------- per-b tail: pools + output MLP
__global__ __launch_bounds__(256) void final_k(
    const float* __restrict__ qall, const float* __restrict__ Kp,
    const float* __restrict__ P, const float* __restrict__ Kd,
    const float* __restrict__ dtok,
    const float* __restrict__ o1w, const float* __restrict__ o1b, const float* __restrict__ pr1,
    const float* __restrict__ o2w, const float* __restrict__ o2b, const float* __restrict__ pr2,
    const float* __restrict__ o3w, const float* __restrict__ o3b,
    float* __restrict__ out)
{
  __shared__ float qa[128];
  __shared__ float sp[10], sd[16], wp[10], wdd[16];
  __shared__ float vcat[256];
  __shared__ float h1[512];
  __shared__ float h2[128];
  __shared__ float redw[4];
  int b = blockIdx.x, t = threadIdx.x;
  if (t < 128) qa[t] = qall[(size_t)b * 128 + t];
  __syncthreads();
  if (t < 10){
    const float* kp = Kp + ((size_t)b * 10 + t) * 128;
    float s = 0.f;
    for (int h = 0; h < 128; ++h) s += qa[h] * kp[h];
    sp[t] = s * 0.088388347648318447f;
  } else if (t >= 64 && t < 80){
    int j = t - 64;
    const float* kd = Kd + ((size_t)b * 16 + j) * 128;
    float s = 0.f;
    for (int h = 0; h < 128; ++h) s += qa[h] * kd[h];
    sd[j] = s * 0.088388347648318447f;
  }
  __syncthreads();
  if (t == 0){
    float mx = -3e38f;
    for (int j = 0; j < 10; ++j) mx = fmaxf(mx, sp[j]);
    float sum = 0.f;
    for (int j = 0; j < 10; ++j) sum += __expf(sp[j] - mx);
    float inv = 1.f / sum;
    for (int j = 0; j < 10; ++j) wp[j] = __expf(sp[j] - mx) * inv;
  } else if (t == 64){
    float mx = -3e38f;
    for (int j = 0; j < 16; ++j) mx = fmaxf(mx, sd[j]);
    float sum = 0.f;
    for (int j = 0; j < 16; ++j) sum += __expf(sd[j] - mx);
    float inv = 1.f / sum;
    for (int j = 0; j < 16; ++j) wdd[j] = __expf(sd[j] - mx) * inv;
  }
  __syncthreads();
  if (t < 128){
    float vd = 0.f, vp = 0.f;
    for (int j = 0; j < 16; ++j) vd += wdd[j] * dtok[((size_t)b * 16 + j) * 128 + t];
    for (int j = 0; j < 10; ++j) vp += wp[j]  * P[((size_t)b * 10 + j) * 128 + t];
    vcat[t] = vd; vcat[128 + t] = vp;
  }
  __syncthreads();
  {
    float p1 = pr1[0];
    float a1 = o1b[t], a2 = o1b[t + 256];
    for (int k = 0; k < 256; ++k){
      float v = vcat[k];
      a1 += v * o1w[(size_t)k * 512 + t];
      a2 += v * o1w[(size_t)k * 512 + t + 256];
    }
    h1[t]       = a1 > 0.f ? a1 : p1 * a1;
    h1[t + 256] = a2 > 0.f ? a2 : p1 * a2;
  }
  __syncthreads();
  if (t < 128){
    float p2 = pr2[0];
    float a = o2b[t];
    for (int k = 0; k < 512; ++k) a += h1[k] * o2w[(size_t)k * 128 + t];
    h2[t] = a > 0.f ? a : p2 * a;
  }
  __syncthreads();
  float v = (t < 128) ? h2[t] * o3w[t] : 0.f;
  #pragma unroll
  for (int m = 32; m >= 1; m >>= 1) v += __shfl_xor(v, m);
  if ((t & 63) == 0) redw[t >> 6] = v;
  __syncthreads();
  if (t == 0) out[b] = redw[0] + redw[1] + redw[2] + redw[3] + o3b[0];
}

// ---------------------------------------------------------------- launch
extern "C" void kernel_launch(void* const* d_in, const int* in_sizes, int n_in,
                              void* d_out, int out_size, void* d_ws, size_t ws_size,
                              hipStream_t stream)
{
  (void)in_sizes; (void)n_in; (void)out_size;
  const float* x        = (const float*)d_in[0];
  const float* pro_emb  = (const float*)d_in[1];
  const int*   pro_batch= (const int*)d_in[2];
  // r_w1..r_b4 (3..10), aq_w (12), aq_b (13), am_w[:,H:]: dead — softmax shift-invariant per segment.
  const float* prej2_w  = (const float*)d_in[11];
  const float* ak_w     = (const float*)d_in[14];
  const float* ak_b     = (const float*)d_in[15];
  const float* am_w     = (const float*)d_in[16];
  const float* fpln_g   = (const float*)d_in[17];
  const float* fpln_b   = (const float*)d_in[18];
  const float* fpproj_w = (const float*)d_in[19];
  const float* fpproj_b = (const float*)d_in[20];
  const float* gdln_g   = (const float*)d_in[21];
  const float* gdln_b   = (const float*)d_in[22];
  const float* gd1_w    = (const float*)d_in[23];
  const float* gd1_b    = (const float*)d_in[24];
  const float* gd2_w    = (const float*)d_in[25];
  const float* gd2_b    = (const float*)d_in[26];
  const float* gp_w     = (const float*)d_in[27];
  const float* gp_b     = (const float*)d_in[28];
  const float* q_w      = (const float*)d_in[29];
  const float* q_b      = (const float*)d_in[30];
  const float* lnd_g    = (const float*)d_in[31];
  const float* lnd_b    = (const float*)d_in[32];
  const float* kd_w     = (const float*)d_in[33];
  const float* kd_b     = (const float*)d_in[34];
  const float* lnp_g    = (const float*)d_in[35];
  const float* lnp_b    = (const float*)d_in[36];
  const float* kp_w     = (const float*)d_in[37];
  const float* kp_b     = (const float*)d_in[38];
  const float* o1_w     = (const float*)d_in[39];
  const float* o1_b     = (const float*)d_in[40];
  const float* pr1      = (const float*)d_in[41];
  const float* o2_w     = (const float*)d_in[42];
  const float* o2_b     = (const float*)d_in[43];
  const float* pr2      = (const float*)d_in[44];
  const float* o3_w     = (const float*)d_in[45];
  const float* o3_b     = (const float*)d_in[46];
  float* out = (float*)d_out;

  float* W = (float*)d_ws;
  size_t off = 0;
  int*   seg   = (int*)W;            off += 256;
  unsigned short* protb = (unsigned short*)(W + off); off += (size_t)65536 * 128 / 2;  // bf16
  unsigned short* prejT = (unsigned short*)(W + off); off += 163840 / 2;               // bf16
  unsigned short* akwT  = (unsigned short*)(W + off); off += 163840 / 2;               // bf16
  float* xln1 = W + off;        off += 128 * 1024;
  float* xln2 = W + off;        off += 128 * 1024;
  float* dtp  = W + off;        off += 128 * 2048;
  float* dtok = W + off;        off += 128 * 2048;
  float* Kd   = W + off;        off += 128 * 2048;
  float* gd1t = W + off;        off += 128 * 128;
  float* gbuf = W + off;        off += 128 * 256;
  float* qall = W + off;        off += 128 * 128;
  float* attp = W + off;        off += 128 * 10 * 128;
  float* attm = W + off;        off += 128 * 128;
  float* Pm   = W + off;        off += 128 * 10 * 128;
  float* Kp   = W + off;        off += 128 * 10 * 128;
  float* part = W + off;        off += (size_t)128 * NCHUNK * 1300;
  if (ws_size < off * sizeof(float)) return;

  segoff_k<<<1, 256, 0, stream>>>(pro_batch, seg);
  cvt_prejT_k<<<640, 256, 0, stream>>>(prej2_w, prejT);
  cvt_akwT_k<<<640, 256, 0, stream>>>(ak_w, akwT);
  ln_x_k<<<128, 256, 0, stream>>>(x, fpln_g, fpln_b, gdln_g, gdln_b, xln1, xln2);
  // prot = relu(pro_emb @ prej2_w) -> bf16   [65536 x 1280 x 128], MFMA
  gemm1_mfma<<<512, 256, 0, stream>>>(pro_emb, prejT, protb);
  // d_tok_pre = LN(x)@fpproj + b     [128 x 1024 x 2048]
  gemm_k<0><<<dim3(2, 16), 256, 0, stream>>>(xln1, fpproj_w, fpproj_b, dtp, 128, 2048, 1024, 1024, 2048);
  ln_rows_k<<<2048, 128, 0, stream>>>(dtp, dtok, lnd_g, lnd_b);
  gemm_k<0><<<dim3(32, 1), 256, 0, stream>>>(dtok, kd_w, kd_b, Kd, 2048, 128, 128, 128, 128);
  // g_d = gelu(LN(x)@gd1 + b)@gd2 + b
  gemm_k<2><<<dim3(2, 1), 256, 0, stream>>>(xln2, gd1_w, gd1_b, gd1t, 128, 128, 1024, 1024, 128);
  gemm_k<0><<<dim3(2, 1), 256, 0, stream>>>(gd1t, gd2_w, gd2_b, gbuf, 128, 128, 128, 128, 256);
  // fused k/score/segment-softmax partials (MFMA)
  seg_attn_mfma<<<128 * NCHUNK, 256, 0, stream>>>(protb, akwT, ak_b, am_w, seg, part);
  merge_k<<<128, 128, 0, stream>>>(part, attp, attm);
  // g_p = gelu(att_mean@gp + b) into gbuf cols 128..255
  gemm_k<2><<<dim3(2, 1), 256, 0, stream>>>(attm, gp_w, gp_b, gbuf + 128, 128, 128, 128, 128, 256);
  // q_all = [g_d, g_p] @ q_w + q_b
  gemm_k<0><<<dim3(2, 1), 256, 0, stream>>>(gbuf, q_w, q_b, qall, 128, 128, 256, 256, 128);
  ln_rows_k<<<1280, 128, 0, stream>>>(attp, Pm, lnp_g, lnp_b);
  gemm_k<0><<<dim3(20, 1), 256, 0, stream>>>(Pm, kp_w, kp_b, Kp, 1280, 128, 128, 128, 128);
  final_k<<<128, 256, 0, stream>>>(qall, Kp, Pm, Kd, dtok,
      o1_w, o1_b, pr1, o2_w, o2_b, pr2, o3_w, o3_b, out);
}